// Round 1
// baseline (62.457 us; speedup 1.0000x reference)
//
#include <hip/hip_runtime.h>

static constexpr int N_SAMPLES = 64;
static constexpr int C = 1024;
static constexpr int BLOCK = 256;
static constexpr int WAVES = BLOCK / 64;

__device__ __forceinline__ float wave_sum(float v) {
#pragma unroll
    for (int off = 32; off > 0; off >>= 1) v += __shfl_down(v, off, 64);
    return v;
}
__device__ __forceinline__ float wave_max(float v) {
#pragma unroll
    for (int off = 32; off > 0; off >>= 1) v = fmaxf(v, __shfl_down(v, off, 64));
    return v;
}

// One block per sample. Analytic collapse of the [C, C] masked-softmax KL:
//   KL_ij = e^{mt-Zt_j} * A + e^{t_j-Zt_j} (t_j - s_j) + (Zs_j - Zt_j)
// with per-sample scalars mt, ms, Et, Es, A over the negative set.
__global__ __launch_bounds__(BLOCK) void psd_kernel(
        const float* __restrict__ student,
        const float* __restrict__ teacher,
        const int*   __restrict__ target,
        float* __restrict__ out) {
    const int i    = blockIdx.x;
    const int tid  = threadIdx.x;
    const int lane = tid & 63;
    const int wave = tid >> 6;

    __shared__ float sh_t[C];
    __shared__ float sh_s[C];
    __shared__ int   sh_g[C];
    __shared__ float redA[WAVES], redB[WAVES], redC[WAVES];

    // Stage rows in LDS: 1024 elems / 256 threads = 1 float4/int4 per thread.
    {
        const float4* t4 = reinterpret_cast<const float4*>(teacher + i * C);
        const float4* s4 = reinterpret_cast<const float4*>(student + i * C);
        const int4*   g4 = reinterpret_cast<const int4*>(target + i * C);
        reinterpret_cast<float4*>(sh_t)[tid] = t4[tid];
        reinterpret_cast<float4*>(sh_s)[tid] = s4[tid];
        reinterpret_cast<int4*>(sh_g)[tid]   = g4[tid];
    }
    __syncthreads();

    // Phase 1: max of teacher/student over negatives (for stable exp sums).
    float mt = -1e30f, ms = -1e30f;
    for (int k = tid; k < C; k += BLOCK) {
        if (sh_g[k] == 0) {
            mt = fmaxf(mt, sh_t[k]);
            ms = fmaxf(ms, sh_s[k]);
        }
    }
    mt = wave_max(mt);
    ms = wave_max(ms);
    if (lane == 0) { redA[wave] = mt; redB[wave] = ms; }
    __syncthreads();
    mt = fmaxf(fmaxf(redA[0], redA[1]), fmaxf(redA[2], redA[3]));
    ms = fmaxf(fmaxf(redB[0], redB[1]), fmaxf(redB[2], redB[3]));
    __syncthreads();

    // Phase 2: Et = sum e^{t-mt}, Es = sum e^{s-ms}, A = sum e^{t-mt}(t-s), negatives only.
    float Et = 0.f, Es = 0.f, A = 0.f;
    for (int k = tid; k < C; k += BLOCK) {
        if (sh_g[k] == 0) {
            float tk = sh_t[k], sk = sh_s[k];
            float et = __expf(tk - mt);
            Et += et;
            Es += __expf(sk - ms);
            A  += et * (tk - sk);
        }
    }
    Et = wave_sum(Et); Es = wave_sum(Es); A = wave_sum(A);
    if (lane == 0) { redA[wave] = Et; redB[wave] = Es; redC[wave] = A; }
    __syncthreads();
    Et = redA[0] + redA[1] + redA[2] + redA[3];
    Es = redB[0] + redB[1] + redB[2] + redB[3];
    A  = redC[0] + redC[1] + redC[2] + redC[3];
    __syncthreads();

    // logsumexp over just the negatives (−inf-ish when the negative set is empty;
    // then KL degenerates to 0 exactly as the reference's NEG_INF masking does).
    float Zt_neg = (Et > 0.f) ? mt + __logf(Et) : -1e30f;
    float Zs_neg = (Es > 0.f) ? ms + __logf(Es) : -1e30f;

    // Phase 3: O(1) per positive class.
    float acc = 0.f;
    for (int k = tid; k < C; k += BLOCK) {
        if (sh_g[k] == 1) {
            float tj = sh_t[k], sj = sh_s[k];
            float a  = fmaxf(Zt_neg, tj);
            float Zt = a + __logf(__expf(Zt_neg - a) + __expf(tj - a));
            float b  = fmaxf(Zs_neg, sj);
            float Zs = b + __logf(__expf(Zs_neg - b) + __expf(sj - b));
            acc += __expf(mt - Zt) * A + __expf(tj - Zt) * (tj - sj) + (Zs - Zt);
        }
    }
    acc = wave_sum(acc);
    if (lane == 0) redA[wave] = acc;
    __syncthreads();
    if (tid == 0) {
        float total = redA[0] + redA[1] + redA[2] + redA[3];
        atomicAdd(out, total * (1.0f / N_SAMPLES));
    }
}

extern "C" void kernel_launch(void* const* d_in, const int* in_sizes, int n_in,
                              void* d_out, int out_size, void* d_ws, size_t ws_size,
                              hipStream_t stream) {
    const float* student = (const float*)d_in[0];
    const float* teacher = (const float*)d_in[1];
    const int*   target  = (const int*)d_in[2];
    float* out = (float*)d_out;

    // d_out is re-poisoned to 0xAA before every launch — zero it for the atomics.
    hipMemsetAsync(out, 0, sizeof(float), stream);
    psd_kernel<<<N_SAMPLES, BLOCK, 0, stream>>>(student, teacher, target, out);
}

// Round 2
// 59.391 us; speedup vs baseline: 1.0516x; 1.0516x over previous
//
#include <hip/hip_runtime.h>

static constexpr int N_SAMPLES = 64;
static constexpr int C = 1024;
static constexpr int BLOCK = 256;          // 1 float4 per thread covers C=1024
static constexpr int WAVES = BLOCK / 64;

__device__ __forceinline__ float wave_sum(float v) {
#pragma unroll
    for (int off = 32; off > 0; off >>= 1) v += __shfl_down(v, off, 64);
    return v;
}
__device__ __forceinline__ float wave_max(float v) {
#pragma unroll
    for (int off = 32; off > 0; off >>= 1) v = fmaxf(v, __shfl_down(v, off, 64));
    return v;
}

// One block per sample; row held entirely in registers (1 float4/int4 per thread).
// Analytic collapse of the [C, C] masked-softmax KL:
//   KL_ij = e^{mt-Zt_j} * A + e^{t_j-Zt_j} (t_j - s_j) + (Zs_j - Zt_j)
// with per-sample scalars mt, ms, Et, Es, A over the negative set.
__global__ __launch_bounds__(BLOCK) void psd_sample_kernel(
        const float* __restrict__ student,
        const float* __restrict__ teacher,
        const int*   __restrict__ target,
        float* __restrict__ per_sample) {
    const int i    = blockIdx.x;
    const int tid  = threadIdx.x;
    const int lane = tid & 63;
    const int wave = tid >> 6;

    __shared__ float redA[WAVES], redB[WAVES], redC[WAVES];

    const float4 tv = reinterpret_cast<const float4*>(teacher + i * C)[tid];
    const float4 sv = reinterpret_cast<const float4*>(student + i * C)[tid];
    const int4   gv = reinterpret_cast<const int4*>(target + i * C)[tid];

    const float tr[4] = {tv.x, tv.y, tv.z, tv.w};
    const float sr[4] = {sv.x, sv.y, sv.z, sv.w};
    const int   gr[4] = {gv.x, gv.y, gv.z, gv.w};

    // Phase 1: max of teacher/student over negatives (for stable exp sums).
    float mt = -1e30f, ms = -1e30f;
#pragma unroll
    for (int k = 0; k < 4; ++k) {
        if (gr[k] == 0) { mt = fmaxf(mt, tr[k]); ms = fmaxf(ms, sr[k]); }
    }
    mt = wave_max(mt);
    ms = wave_max(ms);
    if (lane == 0) { redA[wave] = mt; redB[wave] = ms; }
    __syncthreads();
    mt = fmaxf(fmaxf(redA[0], redA[1]), fmaxf(redA[2], redA[3]));
    ms = fmaxf(fmaxf(redB[0], redB[1]), fmaxf(redB[2], redB[3]));
    __syncthreads();

    // Phase 2: Et = sum e^{t-mt}, Es = sum e^{s-ms}, A = sum e^{t-mt}(t-s); negatives only.
    float Et = 0.f, Es = 0.f, A = 0.f;
#pragma unroll
    for (int k = 0; k < 4; ++k) {
        if (gr[k] == 0) {
            float et = __expf(tr[k] - mt);
            Et += et;
            Es += __expf(sr[k] - ms);
            A  += et * (tr[k] - sr[k]);
        }
    }
    Et = wave_sum(Et); Es = wave_sum(Es); A = wave_sum(A);
    if (lane == 0) { redA[wave] = Et; redB[wave] = Es; redC[wave] = A; }
    __syncthreads();
    Et = redA[0] + redA[1] + redA[2] + redA[3];
    Es = redB[0] + redB[1] + redB[2] + redB[3];
    A  = redC[0] + redC[1] + redC[2] + redC[3];
    __syncthreads();

    // logsumexp over just the negatives (−inf-ish when the negative set is empty;
    // then KL degenerates to 0 exactly as the reference's NEG_INF masking does).
    const float Zt_neg = (Et > 0.f) ? mt + __logf(Et) : -1e30f;
    const float Zs_neg = (Es > 0.f) ? ms + __logf(Es) : -1e30f;

    // Phase 3: O(1) per positive class.
    float acc = 0.f;
#pragma unroll
    for (int k = 0; k < 4; ++k) {
        if (gr[k] == 1) {
            float tj = tr[k], sj = sr[k];
            float a  = fmaxf(Zt_neg, tj);
            float Zt = a + __logf(__expf(Zt_neg - a) + __expf(tj - a));
            float b  = fmaxf(Zs_neg, sj);
            float Zs = b + __logf(__expf(Zs_neg - b) + __expf(sj - b));
            acc += __expf(mt - Zt) * A + __expf(tj - Zt) * (tj - sj) + (Zs - Zt);
        }
    }
    acc = wave_sum(acc);
    if (lane == 0) redA[wave] = acc;
    __syncthreads();
    if (tid == 0) {
        per_sample[i] = redA[0] + redA[1] + redA[2] + redA[3];
    }
}

// Final reduce: 64 per-sample losses -> scalar, scaled by 1/N. Plain store to
// d_out (poisoned 0xAA) — no memset / atomics needed.
__global__ __launch_bounds__(64) void psd_reduce_kernel(
        const float* __restrict__ per_sample, float* __restrict__ out) {
    float v = per_sample[threadIdx.x];
    v = wave_sum(v);
    if (threadIdx.x == 0) out[0] = v * (1.0f / N_SAMPLES);
}

extern "C" void kernel_launch(void* const* d_in, const int* in_sizes, int n_in,
                              void* d_out, int out_size, void* d_ws, size_t ws_size,
                              hipStream_t stream) {
    const float* student = (const float*)d_in[0];
    const float* teacher = (const float*)d_in[1];
    const int*   target  = (const int*)d_in[2];
    float* out = (float*)d_out;
    float* per_sample = (float*)d_ws;   // 64 floats of scratch

    psd_sample_kernel<<<N_SAMPLES, BLOCK, 0, stream>>>(student, teacher, target, per_sample);
    psd_reduce_kernel<<<1, 64, 0, stream>>>(per_sample, out);
}